// Round 2
// baseline (2747.689 us; speedup 1.0000x reference)
//
#include <hip/hip_runtime.h>
#include <stdint.h>

#define B_ 2
#define S_ 2048
#define H_ 2048
#define NH_ 16
#define NKV_ 4
#define DH_ 128
#define I_ 8192
#define M_ (B_*S_)   // 4096 rows

typedef unsigned short u16;
typedef __attribute__((ext_vector_type(8))) short short8;
typedef __attribute__((ext_vector_type(4))) float floatx4;

__device__ __forceinline__ float b2f(u16 h) {
  union { unsigned int u; float f; } v; v.u = ((unsigned int)h) << 16; return v.f;
}
__device__ __forceinline__ u16 f2b(float f) {
  union { float f; unsigned int u; } v; v.f = f;
  unsigned int u = v.u;
  unsigned int r = (u + 0x7FFFu + ((u >> 16) & 1u)) >> 16;
  return (u16)r;
}
__device__ __forceinline__ floatx4 mfma16(short8 a, short8 b, floatx4 c) {
  return __builtin_amdgcn_mfma_f32_16x16x32_bf16(a, b, c, 0, 0, 0);
}

// ---------------- RMSNorm over H=2048: f32 in, bf16 out. One row/block ----
__global__ __launch_bounds__(256) void rmsnorm_kernel(const float* __restrict__ x,
                                                      const float* __restrict__ w,
                                                      u16* __restrict__ o) {
  int row = blockIdx.x;
  int tid = threadIdx.x;
  const float* xr = x + (size_t)row * H_ + tid * 8;
  float4 a = *(const float4*)xr;
  float4 b = *(const float4*)(xr + 4);
  float xf[8] = {a.x, a.y, a.z, a.w, b.x, b.y, b.z, b.w};
  float ss = 0.f;
#pragma unroll
  for (int i = 0; i < 8; ++i) ss += xf[i] * xf[i];
#pragma unroll
  for (int m = 32; m >= 1; m >>= 1) ss += __shfl_xor(ss, m, 64);
  __shared__ float red[4];
  if ((tid & 63) == 0) red[tid >> 6] = ss;
  __syncthreads();
  float tot = red[0] + red[1] + red[2] + red[3];
  float scale = rsqrtf(tot / (float)H_ + 1e-6f);
  const float* wr = w + tid * 8;
  float4 wa = *(const float4*)wr;
  float4 wb = *(const float4*)(wr + 4);
  float wf[8] = {wa.x, wa.y, wa.z, wa.w, wb.x, wb.y, wb.z, wb.w};
  u16 ov[8];
#pragma unroll
  for (int i = 0; i < 8; ++i) ov[i] = f2b(xf[i] * scale * wf[i]);
  *(uint4*)&o[(size_t)row * H_ + tid * 8] = *(uint4*)ov;
}

// ------- GEMM: C = A_bf16(M,K) @ B_f32(K,N) [+ Res_f32]; out bf16 or f32 ---
// 64x64 tile, K-step 32, 4 waves each 32x32 via 2x2 MFMA 16x16x32.
template <bool OUTF>
__global__ __launch_bounds__(256) void gemm_kernel(const u16* __restrict__ A,
                                                   const float* __restrict__ Bm,
                                                   void* __restrict__ Cv,
                                                   const float* __restrict__ Res,
                                                   int M, int N, int K) {
  __shared__ u16 sa[64][40];   // [m][k] pad +8
  __shared__ u16 sb[64][40];   // [n][k] transposed, pad +8
  int tid = threadIdx.x;
  int lane = tid & 63, w = tid >> 6;
  int q4 = lane >> 4, l15 = lane & 15;
  int wm = (w >> 1) * 32, wn = (w & 1) * 32;
  int m0 = blockIdx.y * 64, n0 = blockIdx.x * 64;
  int arow = tid >> 2, acol = (tid & 3) * 8;   // A tile 64x32
  int brow = tid >> 3, bcol = (tid & 7) * 8;   // B tile 32(k) x 64(n)
  floatx4 acc[2][2] = {};
  const u16* aptr = A + (size_t)(m0 + arow) * K + acol;
  const float* bptr = Bm + (size_t)brow * N + n0 + bcol;
  for (int k0 = 0; k0 < K; k0 += 32) {
    uint4 av = *(const uint4*)(aptr + k0);
    float4 b0 = *(const float4*)(bptr + (size_t)k0 * N);
    float4 b1 = *(const float4*)(bptr + (size_t)k0 * N + 4);
    *(uint4*)&sa[arow][acol] = av;
    float bf[8] = {b0.x, b0.y, b0.z, b0.w, b1.x, b1.y, b1.z, b1.w};
#pragma unroll
    for (int j = 0; j < 8; ++j) sb[bcol + j][brow] = f2b(bf[j]);
    __syncthreads();
    short8 af0 = *(const short8*)&sa[wm + l15][q4 * 8];
    short8 af1 = *(const short8*)&sa[wm + 16 + l15][q4 * 8];
    short8 bf0 = *(const short8*)&sb[wn + l15][q4 * 8];
    short8 bf1 = *(const short8*)&sb[wn + 16 + l15][q4 * 8];
    acc[0][0] = mfma16(af0, bf0, acc[0][0]);
    acc[0][1] = mfma16(af0, bf1, acc[0][1]);
    acc[1][0] = mfma16(af1, bf0, acc[1][0]);
    acc[1][1] = mfma16(af1, bf1, acc[1][1]);
    __syncthreads();
  }
#pragma unroll
  for (int i = 0; i < 2; ++i)
#pragma unroll
    for (int j = 0; j < 2; ++j)
#pragma unroll
      for (int r = 0; r < 4; ++r) {
        int row = m0 + wm + i * 16 + q4 * 4 + r;
        int col = n0 + wn + j * 16 + l15;
        float v = acc[i][j][r];
        if (Res) v += Res[(size_t)row * N + col];
        if (OUTF) ((float*)Cv)[(size_t)row * N + col] = v;
        else      ((u16*)Cv)[(size_t)row * N + col] = f2b(v);
      }
}

// ------- fused gate/up GEMM + SiLU(g)*u: out bf16 --------------------------
__global__ __launch_bounds__(256) void gateup_kernel(const u16* __restrict__ A,
                                                     const float* __restrict__ G,
                                                     const float* __restrict__ U,
                                                     u16* __restrict__ O,
                                                     int M, int N, int K) {
  __shared__ u16 sa[64][40];
  __shared__ u16 sg[64][40];
  __shared__ u16 su[64][40];
  int tid = threadIdx.x;
  int lane = tid & 63, w = tid >> 6;
  int q4 = lane >> 4, l15 = lane & 15;
  int wm = (w >> 1) * 32, wn = (w & 1) * 32;
  int m0 = blockIdx.y * 64, n0 = blockIdx.x * 64;
  int arow = tid >> 2, acol = (tid & 3) * 8;
  int brow = tid >> 3, bcol = (tid & 7) * 8;
  floatx4 accg[2][2] = {};
  floatx4 accu[2][2] = {};
  const u16* aptr = A + (size_t)(m0 + arow) * K + acol;
  const float* gptr = G + (size_t)brow * N + n0 + bcol;
  const float* uptr = U + (size_t)brow * N + n0 + bcol;
  for (int k0 = 0; k0 < K; k0 += 32) {
    uint4 av = *(const uint4*)(aptr + k0);
    float4 g0 = *(const float4*)(gptr + (size_t)k0 * N);
    float4 g1 = *(const float4*)(gptr + (size_t)k0 * N + 4);
    float4 u0 = *(const float4*)(uptr + (size_t)k0 * N);
    float4 u1 = *(const float4*)(uptr + (size_t)k0 * N + 4);
    *(uint4*)&sa[arow][acol] = av;
    float gf[8] = {g0.x, g0.y, g0.z, g0.w, g1.x, g1.y, g1.z, g1.w};
    float uf[8] = {u0.x, u0.y, u0.z, u0.w, u1.x, u1.y, u1.z, u1.w};
#pragma unroll
    for (int j = 0; j < 8; ++j) {
      sg[bcol + j][brow] = f2b(gf[j]);
      su[bcol + j][brow] = f2b(uf[j]);
    }
    __syncthreads();
    short8 af0 = *(const short8*)&sa[wm + l15][q4 * 8];
    short8 af1 = *(const short8*)&sa[wm + 16 + l15][q4 * 8];
    short8 gf0 = *(const short8*)&sg[wn + l15][q4 * 8];
    short8 gf1 = *(const short8*)&sg[wn + 16 + l15][q4 * 8];
    short8 uf0 = *(const short8*)&su[wn + l15][q4 * 8];
    short8 uf1 = *(const short8*)&su[wn + 16 + l15][q4 * 8];
    accg[0][0] = mfma16(af0, gf0, accg[0][0]);
    accg[0][1] = mfma16(af0, gf1, accg[0][1]);
    accg[1][0] = mfma16(af1, gf0, accg[1][0]);
    accg[1][1] = mfma16(af1, gf1, accg[1][1]);
    accu[0][0] = mfma16(af0, uf0, accu[0][0]);
    accu[0][1] = mfma16(af0, uf1, accu[0][1]);
    accu[1][0] = mfma16(af1, uf0, accu[1][0]);
    accu[1][1] = mfma16(af1, uf1, accu[1][1]);
    __syncthreads();
  }
#pragma unroll
  for (int i = 0; i < 2; ++i)
#pragma unroll
    for (int j = 0; j < 2; ++j)
#pragma unroll
      for (int r = 0; r < 4; ++r) {
        int row = m0 + wm + i * 16 + q4 * 4 + r;
        int col = n0 + wn + j * 16 + l15;
        float g = accg[i][j][r];
        float u = accu[i][j][r];
        float s = g / (1.f + __expf(-g));
        O[(size_t)row * N + col] = f2b(s * u);
      }
}

// ------- per-head RMSNorm + RoPE (in place on bf16), 1 wave per (t,h) -----
__global__ __launch_bounds__(256) void qknorm_rope_kernel(u16* __restrict__ x,
                                                          const float* __restrict__ nw,
                                                          const float* __restrict__ cs,
                                                          const float* __restrict__ sn,
                                                          int nheads) {
  int lane = threadIdx.x & 63;
  int w = threadIdx.x >> 6;
  int gw = blockIdx.x * 4 + w;
  int t = gw / nheads, h = gw % nheads;
  u16* xp = x + ((size_t)t * nheads + h) * DH_;
  float x0 = b2f(xp[lane]), x1 = b2f(xp[lane + 64]);
  float ss = x0 * x0 + x1 * x1;
#pragma unroll
  for (int m = 32; m >= 1; m >>= 1) ss += __shfl_xor(ss, m, 64);
  float scale = rsqrtf(ss / 128.f + 1e-6f);
  float n0 = x0 * scale * nw[lane];
  float n1 = x1 * scale * nw[lane + 64];
  const float* cp = cs + (size_t)t * DH_;
  const float* sp = sn + (size_t)t * DH_;
  float c0 = cp[lane], c1 = cp[lane + 64];
  float s0 = sp[lane], s1 = sp[lane + 64];
  xp[lane]      = f2b(n0 * c0 - n1 * s0);
  xp[lane + 64] = f2b(n1 * c1 + n0 * s1);
}

// ---------------- flash attention (full, non-causal), GQA, all bf16 -------
__global__ __launch_bounds__(256) void attn_kernel(const u16* __restrict__ qb,
                                                   const u16* __restrict__ kb,
                                                   const u16* __restrict__ vb,
                                                   u16* __restrict__ ob) {
  __shared__ u16 q_lds[64][136];
  __shared__ u16 k_lds[64][136];
  __shared__ u16 vt_lds[128][72];   // [d][j]
  __shared__ u16 p_lds[4][16][72];  // per wave [qrow][j]
  int tid = threadIdx.x;
  int lane = tid & 63, w = tid >> 6;
  int q4 = lane >> 4, l15 = lane & 15;
  int qt = blockIdx.x & 31;
  int h = (blockIdx.x >> 5) & 15;
  int b = blockIdx.x >> 9;
  int kvh = h >> 2;
  int srow = tid >> 2;
  int sd0 = (tid & 3) * 32;
  const float scaling = 0.08838834764831845f;

  {
    const u16* qsrc = qb + (size_t)(b * S_ + qt * 64 + srow) * (NH_ * DH_) + h * DH_;
#pragma unroll
    for (int ii = 0; ii < 4; ++ii) {
      int d = sd0 + ii * 8;
      *(uint4*)&q_lds[srow][d] = *(const uint4*)&qsrc[d];
    }
  }

  float m_i[4], l_i[4];
  floatx4 o_acc[8] = {};
#pragma unroll
  for (int r = 0; r < 4; ++r) { m_i[r] = -1e30f; l_i[r] = 0.f; }

  for (int c = 0; c < S_ / 64; ++c) {
    int j0 = c * 64;
    __syncthreads();
    const u16* ksrc = kb + (size_t)(b * S_ + j0 + srow) * (NKV_ * DH_) + kvh * DH_;
    const u16* vsrc = vb + (size_t)(b * S_ + j0 + srow) * (NKV_ * DH_) + kvh * DH_;
#pragma unroll
    for (int ii = 0; ii < 4; ++ii) {
      int d = sd0 + ii * 8;
      *(uint4*)&k_lds[srow][d] = *(const uint4*)&ksrc[d];
      uint4 vv = *(const uint4*)&vsrc[d];
      const u16* ve = (const u16*)&vv;
#pragma unroll
      for (int e = 0; e < 8; ++e) vt_lds[d + e][srow] = ve[e];
    }
    __syncthreads();

    floatx4 sc[4];
#pragma unroll
    for (int js = 0; js < 4; ++js) {
      floatx4 a = {};
#pragma unroll
      for (int kk = 0; kk < 4; ++kk) {
        short8 qa  = *(const short8*)&q_lds[w * 16 + l15][kk * 32 + q4 * 8];
        short8 kbf = *(const short8*)&k_lds[js * 16 + l15][kk * 32 + q4 * 8];
        a = mfma16(qa, kbf, a);
      }
      sc[js] = a;
    }
    float mx[4];
#pragma unroll
    for (int r = 0; r < 4; ++r)
      mx[r] = fmaxf(fmaxf(sc[0][r], sc[1][r]), fmaxf(sc[2][r], sc[3][r])) * scaling;
#pragma unroll
    for (int m = 8; m >= 1; m >>= 1)
#pragma unroll
      for (int r = 0; r < 4; ++r) mx[r] = fmaxf(mx[r], __shfl_xor(mx[r], m, 64));
    float alpha[4], rs[4];
#pragma unroll
    for (int r = 0; r < 4; ++r) {
      float mnew = fmaxf(m_i[r], mx[r]);
      alpha[r] = __expf(m_i[r] - mnew);
      m_i[r] = mnew;
      rs[r] = 0.f;
    }
#pragma unroll
    for (int js = 0; js < 4; ++js)
#pragma unroll
      for (int r = 0; r < 4; ++r) {
        float p = __expf(sc[js][r] * scaling - m_i[r]);
        rs[r] += p;
        p_lds[w][q4 * 4 + r][js * 16 + l15] = f2b(p);
      }
#pragma unroll
    for (int m = 8; m >= 1; m >>= 1)
#pragma unroll
      for (int r = 0; r < 4; ++r) rs[r] += __shfl_xor(rs[r], m, 64);
#pragma unroll
    for (int r = 0; r < 4; ++r) l_i[r] = l_i[r] * alpha[r] + rs[r];
#pragma unroll
    for (int d2 = 0; d2 < 8; ++d2)
#pragma unroll
      for (int r = 0; r < 4; ++r) o_acc[d2][r] *= alpha[r];
    __syncthreads();
#pragma unroll
    for (int d2 = 0; d2 < 8; ++d2) {
#pragma unroll
      for (int kk = 0; kk < 2; ++kk) {
        short8 pa  = *(const short8*)&p_lds[w][l15][kk * 32 + q4 * 8];
        short8 vbf = *(const short8*)&vt_lds[d2 * 16 + l15][kk * 32 + q4 * 8];
        o_acc[d2] = mfma16(pa, vbf, o_acc[d2]);
      }
    }
  }
#pragma unroll
  for (int d2 = 0; d2 < 8; ++d2)
#pragma unroll
    for (int r = 0; r < 4; ++r) {
      int row = qt * 64 + w * 16 + q4 * 4 + r;
      float val = o_acc[d2][r] / l_i[r];
      ob[(size_t)(b * S_ + row) * (NH_ * DH_) + h * DH_ + d2 * 16 + l15] = f2b(val);
    }
}

extern "C" void kernel_launch(void* const* d_in, const int* in_sizes, int n_in,
                              void* d_out, int out_size, void* d_ws, size_t ws_size,
                              hipStream_t stream) {
  const float* hs   = (const float*)d_in[0];
  const float* cosb = (const float*)d_in[1];
  const float* sinb = (const float*)d_in[2];
  const float* wq   = (const float*)d_in[3];
  const float* wk   = (const float*)d_in[4];
  const float* wv   = (const float*)d_in[5];
  const float* wo   = (const float*)d_in[6];
  const float* qnw  = (const float*)d_in[7];
  const float* knw  = (const float*)d_in[8];
  const float* anw  = (const float*)d_in[9];
  const float* mnw  = (const float*)d_in[10];
  const float* wg   = (const float*)d_in[11];
  const float* wu   = (const float*)d_in[12];
  const float* wd   = (const float*)d_in[13];
  float* out = (float*)d_out;
  u16* ws  = (u16*)d_ws;

  // ws layout (u16 units). Total 136 MB.
  u16* xn   = ws;                          // 8388608  bf16 (also attn out, also x2)
  u16* qbuf = ws + 8388608;                // 8388608  bf16
  u16* kbuf = ws + 16777216;               // 2097152  bf16
  u16* vbuf = ws + 18874368;               // 2097152  bf16
  u16* hbuf = ws + 20971520;               // 33554432 bf16 (silu(g)*u)
  float* h1 = (float*)(ws + 54525952);     // 8388608  f32

  rmsnorm_kernel<<<M_, 256, 0, stream>>>(hs, anw, xn);
  gemm_kernel<false><<<dim3(2048/64, M_/64), 256, 0, stream>>>(xn, wq, qbuf, nullptr, M_, 2048, 2048);
  gemm_kernel<false><<<dim3(512/64,  M_/64), 256, 0, stream>>>(xn, wk, kbuf, nullptr, M_, 512, 2048);
  gemm_kernel<false><<<dim3(512/64,  M_/64), 256, 0, stream>>>(xn, wv, vbuf, nullptr, M_, 512, 2048);
  qknorm_rope_kernel<<<M_ * NH_  / 4, 256, 0, stream>>>(qbuf, qnw, cosb, sinb, NH_);
  qknorm_rope_kernel<<<M_ * NKV_ / 4, 256, 0, stream>>>(kbuf, knw, cosb, sinb, NKV_);
  attn_kernel<<<B_ * NH_ * (S_ / 64), 256, 0, stream>>>(qbuf, kbuf, vbuf, xn);
  gemm_kernel<true><<<dim3(2048/64, M_/64), 256, 0, stream>>>(xn, wo, h1, hs, M_, 2048, 2048);
  rmsnorm_kernel<<<M_, 256, 0, stream>>>(h1, mnw, xn);
  gateup_kernel<<<dim3(8192/64, M_/64), 256, 0, stream>>>(xn, wg, wu, hbuf, M_, 8192, 2048);
  gemm_kernel<true><<<dim3(2048/64, M_/64), 256, 0, stream>>>(hbuf, wd, out, h1, M_, 2048, 8192);
}

// Round 3
// 1563.828 us; speedup vs baseline: 1.7570x; 1.7570x over previous
//
#include <hip/hip_runtime.h>
#include <stdint.h>

#define B_ 2
#define S_ 2048
#define H_ 2048
#define NH_ 16
#define NKV_ 4
#define DH_ 128
#define I_ 4096
#define M_ (B_*S_)   // 4096 rows
#define IM_ 8192     // intermediate dim

typedef unsigned short u16;
typedef __attribute__((ext_vector_type(8))) short short8;
typedef __attribute__((ext_vector_type(4))) float floatx4;

__device__ __forceinline__ float b2f(u16 h) {
  union { unsigned int u; float f; } v; v.u = ((unsigned int)h) << 16; return v.f;
}
__device__ __forceinline__ u16 f2b(float f) {
  union { float f; unsigned int u; } v; v.f = f;
  unsigned int u = v.u;
  unsigned int r = (u + 0x7FFFu + ((u >> 16) & 1u)) >> 16;
  return (u16)r;
}
__device__ __forceinline__ floatx4 mfma16(short8 a, short8 b, floatx4 c) {
  return __builtin_amdgcn_mfma_f32_16x16x32_bf16(a, b, c, 0, 0, 0);
}
// async global->LDS, 16B per lane. LDS dest = wave-uniform base + lane*16.
__device__ __forceinline__ void gld16(const u16* g, u16* l) {
  __builtin_amdgcn_global_load_lds(
      (const __attribute__((address_space(1))) unsigned int*)g,
      (__attribute__((address_space(3))) unsigned int*)l, 16, 0, 0);
}

// ---- weight convert+transpose: f32 (K,N) -> bf16 (N,K), 64x64 tiles ------
__global__ __launch_bounds__(256) void transpose_kernel(const float* __restrict__ Bm,
                                                        u16* __restrict__ BT,
                                                        int K, int N) {
  __shared__ u16 sl[64][68];
  int t = threadIdx.x;
  int n0 = blockIdx.x * 64, k0 = blockIdx.y * 64;
#pragma unroll
  for (int p = 0; p < 4; ++p) {
    int kk = p * 16 + (t >> 4);
    int nn = (t & 15) * 4;
    float4 v = *(const float4*)&Bm[(size_t)(k0 + kk) * N + n0 + nn];
    sl[kk][nn + 0] = f2b(v.x); sl[kk][nn + 1] = f2b(v.y);
    sl[kk][nn + 2] = f2b(v.z); sl[kk][nn + 3] = f2b(v.w);
  }
  __syncthreads();
#pragma unroll
  for (int p = 0; p < 2; ++p) {
    int nn = p * 32 + (t >> 3);
    int kc = (t & 7) * 8;
    u16 ov[8];
#pragma unroll
    for (int j = 0; j < 8; ++j) ov[j] = sl[kc + j][nn];
    *(uint4*)&BT[(size_t)(n0 + nn) * K + k0 + kc] = *(uint4*)ov;
  }
}

// ---------------- RMSNorm over H=2048: f32 in, bf16 out. One row/block ----
__global__ __launch_bounds__(256) void rmsnorm_kernel(const float* __restrict__ x,
                                                      const float* __restrict__ w,
                                                      u16* __restrict__ o) {
  int row = blockIdx.x;
  int tid = threadIdx.x;
  const float* xr = x + (size_t)row * H_ + tid * 8;
  float4 a = *(const float4*)xr;
  float4 b = *(const float4*)(xr + 4);
  float xf[8] = {a.x, a.y, a.z, a.w, b.x, b.y, b.z, b.w};
  float ss = 0.f;
#pragma unroll
  for (int i = 0; i < 8; ++i) ss += xf[i] * xf[i];
#pragma unroll
  for (int m = 32; m >= 1; m >>= 1) ss += __shfl_xor(ss, m, 64);
  __shared__ float red[4];
  if ((tid & 63) == 0) red[tid >> 6] = ss;
  __syncthreads();
  float tot = red[0] + red[1] + red[2] + red[3];
  float scale = rsqrtf(tot / (float)H_ + 1e-6f);
  const float* wr = w + tid * 8;
  float4 wa = *(const float4*)wr;
  float4 wb = *(const float4*)(wr + 4);
  float wf[8] = {wa.x, wa.y, wa.z, wa.w, wb.x, wb.y, wb.z, wb.w};
  u16 ov[8];
#pragma unroll
  for (int i = 0; i < 8; ++i) ov[i] = f2b(xf[i] * scale * wf[i]);
  *(uint4*)&o[(size_t)row * H_ + tid * 8] = *(uint4*)ov;
}

// ---- m97-style GEMM: C(M,N) = A_bf16(M,K) @ BT_bf16(N,K)^T [+Res_f32] ----
// 128x128 block tile, 4 waves (2x2), wave tile 64x64 (4x4 MFMA 16x16x32),
// BK=32, global_load_lds width-16 staging, unpadded LDS [row][32].
template <int OUTF>   // 0: bf16 out; 1: f32 out (+Res if non-null)
__global__ __launch_bounds__(256) void gemm_t(const u16* __restrict__ A,
                                              const u16* __restrict__ BT,
                                              void* __restrict__ Cv,
                                              const float* __restrict__ Res,
                                              int M, int N, int K) {
  __shared__ u16 sa[128 * 32];
  __shared__ u16 sb[128 * 32];
  const int tid = threadIdx.x;
  const int lane = tid & 63, w = tid >> 6;
  const int q4 = lane >> 4, l15 = lane & 15;
  const int wr = (w >> 1) * 64, wc = (w & 1) * 64;
  const int m0 = blockIdx.y * 128, n0 = blockIdx.x * 128;
  const int srow = lane >> 2, skc = (lane & 3) * 8;
  const int c0 = w * 2;
  floatx4 acc[4][4] = {};
  const u16* aG0 = A  + (size_t)(m0 + (c0 + 0) * 16 + srow) * K + skc;
  const u16* aG1 = A  + (size_t)(m0 + (c0 + 1) * 16 + srow) * K + skc;
  const u16* bG0 = BT + (size_t)(n0 + (c0 + 0) * 16 + srow) * K + skc;
  const u16* bG1 = BT + (size_t)(n0 + (c0 + 1) * 16 + srow) * K + skc;
  u16* aL0 = sa + (c0 + 0) * 512;
  u16* aL1 = sa + (c0 + 1) * 512;
  u16* bL0 = sb + (c0 + 0) * 512;
  u16* bL1 = sb + (c0 + 1) * 512;

  for (int k0 = 0; k0 < K; k0 += 32) {
    __syncthreads();
    gld16(aG0 + k0, aL0);
    gld16(aG1 + k0, aL1);
    gld16(bG0 + k0, bL0);
    gld16(bG1 + k0, bL1);
    __syncthreads();
    short8 af[4], bf[4];
#pragma unroll
    for (int i = 0; i < 4; ++i)
      af[i] = *(const short8*)&sa[(wr + i * 16 + l15) * 32 + q4 * 8];
#pragma unroll
    for (int j = 0; j < 4; ++j)
      bf[j] = *(const short8*)&sb[(wc + j * 16 + l15) * 32 + q4 * 8];
#pragma unroll
    for (int i = 0; i < 4; ++i)
#pragma unroll
      for (int j = 0; j < 4; ++j)
        acc[i][j] = mfma16(af[i], bf[j], acc[i][j]);
  }
#pragma unroll
  for (int i = 0; i < 4; ++i)
#pragma unroll
    for (int j = 0; j < 4; ++j)
#pragma unroll
      for (int r = 0; r < 4; ++r) {
        int row = m0 + wr + i * 16 + q4 * 4 + r;
        int col = n0 + wc + j * 16 + l15;
        float v = acc[i][j][r];
        if (OUTF) {
          if (Res) v += Res[(size_t)row * N + col];
          ((float*)Cv)[(size_t)row * N + col] = v;
        } else {
          ((u16*)Cv)[(size_t)row * N + col] = f2b(v);
        }
      }
}

// ---- fused gate/up GEMM + SiLU(g)*u epilogue, same m97 structure ---------
__global__ __launch_bounds__(256) void gateup_kernel(const u16* __restrict__ A,
                                                     const u16* __restrict__ GT,
                                                     const u16* __restrict__ UT,
                                                     u16* __restrict__ O,
                                                     int M, int N, int K) {
  __shared__ u16 sa[128 * 32];
  __shared__ u16 sg[128 * 32];
  __shared__ u16 su[128 * 32];
  const int tid = threadIdx.x;
  const int lane = tid & 63, w = tid >> 6;
  const int q4 = lane >> 4, l15 = lane & 15;
  const int wr = (w >> 1) * 64, wc = (w & 1) * 64;
  const int m0 = blockIdx.y * 128, n0 = blockIdx.x * 128;
  const int srow = lane >> 2, skc = (lane & 3) * 8;
  const int c0 = w * 2;
  floatx4 accg[4][4] = {};
  floatx4 accu[4][4] = {};
  const u16* aG0 = A  + (size_t)(m0 + (c0 + 0) * 16 + srow) * K + skc;
  const u16* aG1 = A  + (size_t)(m0 + (c0 + 1) * 16 + srow) * K + skc;
  const u16* gG0 = GT + (size_t)(n0 + (c0 + 0) * 16 + srow) * K + skc;
  const u16* gG1 = GT + (size_t)(n0 + (c0 + 1) * 16 + srow) * K + skc;
  const u16* uG0 = UT + (size_t)(n0 + (c0 + 0) * 16 + srow) * K + skc;
  const u16* uG1 = UT + (size_t)(n0 + (c0 + 1) * 16 + srow) * K + skc;
  u16* aL0 = sa + (c0 + 0) * 512; u16* aL1 = sa + (c0 + 1) * 512;
  u16* gL0 = sg + (c0 + 0) * 512; u16* gL1 = sg + (c0 + 1) * 512;
  u16* uL0 = su + (c0 + 0) * 512; u16* uL1 = su + (c0 + 1) * 512;

  for (int k0 = 0; k0 < K; k0 += 32) {
    __syncthreads();
    gld16(aG0 + k0, aL0);
    gld16(aG1 + k0, aL1);
    gld16(gG0 + k0, gL0);
    gld16(gG1 + k0, gL1);
    gld16(uG0 + k0, uL0);
    gld16(uG1 + k0, uL1);
    __syncthreads();
    short8 af[4], gf[4], uf[4];
#pragma unroll
    for (int i = 0; i < 4; ++i)
      af[i] = *(const short8*)&sa[(wr + i * 16 + l15) * 32 + q4 * 8];
#pragma unroll
    for (int j = 0; j < 4; ++j) {
      gf[j] = *(const short8*)&sg[(wc + j * 16 + l15) * 32 + q4 * 8];
      uf[j] = *(const short8*)&su[(wc + j * 16 + l15) * 32 + q4 * 8];
    }
#pragma unroll
    for (int i = 0; i < 4; ++i)
#pragma unroll
      for (int j = 0; j < 4; ++j) {
        accg[i][j] = mfma16(af[i], gf[j], accg[i][j]);
        accu[i][j] = mfma16(af[i], uf[j], accu[i][j]);
      }
  }
#pragma unroll
  for (int i = 0; i < 4; ++i)
#pragma unroll
    for (int j = 0; j < 4; ++j)
#pragma unroll
      for (int r = 0; r < 4; ++r) {
        int row = m0 + wr + i * 16 + q4 * 4 + r;
        int col = n0 + wc + j * 16 + l15;
        float g = accg[i][j][r];
        float u = accu[i][j][r];
        float s = g / (1.f + __expf(-g));
        O[(size_t)row * N + col] = f2b(s * u);
      }
}

// ------- per-head RMSNorm + RoPE (in place on bf16), 1 wave per (t,h) -----
__global__ __launch_bounds__(256) void qknorm_rope_kernel(u16* __restrict__ x,
                                                          const float* __restrict__ nw,
                                                          const float* __restrict__ cs,
                                                          const float* __restrict__ sn,
                                                          int nheads, int rowStride) {
  int lane = threadIdx.x & 63;
  int w = threadIdx.x >> 6;
  int gw = blockIdx.x * 4 + w;
  int t = gw / nheads, h = gw % nheads;
  u16* xp = x + (size_t)t * rowStride + h * DH_;
  float x0 = b2f(xp[lane]), x1 = b2f(xp[lane + 64]);
  float ss = x0 * x0 + x1 * x1;
#pragma unroll
  for (int m = 32; m >= 1; m >>= 1) ss += __shfl_xor(ss, m, 64);
  float scale = rsqrtf(ss / 128.f + 1e-6f);
  float n0 = x0 * scale * nw[lane];
  float n1 = x1 * scale * nw[lane + 64];
  const float* cp = cs + (size_t)t * DH_;
  const float* sp = sn + (size_t)t * DH_;
  float c0 = cp[lane], c1 = cp[lane + 64];
  float s0 = sp[lane], s1 = sp[lane + 64];
  xp[lane]      = f2b(n0 * c0 - n1 * s0);
  xp[lane + 64] = f2b(n1 * c1 + n0 * s1);
}

// ---------------- flash attention (full, non-causal), GQA, all bf16 -------
__global__ __launch_bounds__(256) void attn_kernel(const u16* __restrict__ qb,
                                                   const u16* __restrict__ kb,
                                                   const u16* __restrict__ vb,
                                                   u16* __restrict__ ob) {
  __shared__ u16 q_lds[64][136];
  __shared__ u16 k_lds[64][136];
  __shared__ u16 vt_lds[128][72];   // [d][j]
  __shared__ u16 p_lds[4][16][72];  // per wave [qrow][j]
  const int QSTR = NH_ * DH_ + NKV_ * DH_ * 2;  // 3072 row stride in qkv buffer
  int tid = threadIdx.x;
  int lane = tid & 63, w = tid >> 6;
  int q4 = lane >> 4, l15 = lane & 15;
  int qt = blockIdx.x & 31;
  int h = (blockIdx.x >> 5) & 15;
  int b = blockIdx.x >> 9;
  int kvh = h >> 2;
  int srow = tid >> 2;
  int sd0 = (tid & 3) * 32;
  const float scaling = 0.08838834764831845f;

  {
    const u16* qsrc = qb + (size_t)(b * S_ + qt * 64 + srow) * QSTR + h * DH_;
#pragma unroll
    for (int ii = 0; ii < 4; ++ii) {
      int d = sd0 + ii * 8;
      *(uint4*)&q_lds[srow][d] = *(const uint4*)&qsrc[d];
    }
  }

  float m_i[4], l_i[4];
  floatx4 o_acc[8] = {};
#pragma unroll
  for (int r = 0; r < 4; ++r) { m_i[r] = -1e30f; l_i[r] = 0.f; }

  for (int c = 0; c < S_ / 64; ++c) {
    int j0 = c * 64;
    __syncthreads();
    const u16* ksrc = kb + (size_t)(b * S_ + j0 + srow) * QSTR + kvh * DH_;
    const u16* vsrc = vb + (size_t)(b * S_ + j0 + srow) * QSTR + kvh * DH_;
#pragma unroll
    for (int ii = 0; ii < 4; ++ii) {
      int d = sd0 + ii * 8;
      *(uint4*)&k_lds[srow][d] = *(const uint4*)&ksrc[d];
      uint4 vv = *(const uint4*)&vsrc[d];
      const u16* ve = (const u16*)&vv;
#pragma unroll
      for (int e = 0; e < 8; ++e) vt_lds[d + e][srow] = ve[e];
    }
    __syncthreads();

    floatx4 sc[4];
#pragma unroll
    for (int js = 0; js < 4; ++js) {
      floatx4 a = {};
#pragma unroll
      for (int kk = 0; kk < 4; ++kk) {
        short8 qa  = *(const short8*)&q_lds[w * 16 + l15][kk * 32 + q4 * 8];
        short8 kbf = *(const short8*)&k_lds[js * 16 + l15][kk * 32 + q4 * 8];
        a = mfma16(qa, kbf, a);
      }
      sc[js] = a;
    }
    float mx[4];
#pragma unroll
    for (int r = 0; r < 4; ++r)
      mx[r] = fmaxf(fmaxf(sc[0][r], sc[1][r]), fmaxf(sc[2][r], sc[3][r])) * scaling;
#pragma unroll
    for (int m = 8; m >= 1; m >>= 1)
#pragma unroll
      for (int r = 0; r < 4; ++r) mx[r] = fmaxf(mx[r], __shfl_xor(mx[r], m, 64));
    float alpha[4], rs[4];
#pragma unroll
    for (int r = 0; r < 4; ++r) {
      float mnew = fmaxf(m_i[r], mx[r]);
      alpha[r] = __expf(m_i[r] - mnew);
      m_i[r] = mnew;
      rs[r] = 0.f;
    }
#pragma unroll
    for (int js = 0; js < 4; ++js)
#pragma unroll
      for (int r = 0; r < 4; ++r) {
        float p = __expf(sc[js][r] * scaling - m_i[r]);
        rs[r] += p;
        p_lds[w][q4 * 4 + r][js * 16 + l15] = f2b(p);
      }
#pragma unroll
    for (int m = 8; m >= 1; m >>= 1)
#pragma unroll
      for (int r = 0; r < 4; ++r) rs[r] += __shfl_xor(rs[r], m, 64);
#pragma unroll
    for (int r = 0; r < 4; ++r) l_i[r] = l_i[r] * alpha[r] + rs[r];
#pragma unroll
    for (int d2 = 0; d2 < 8; ++d2)
#pragma unroll
      for (int r = 0; r < 4; ++r) o_acc[d2][r] *= alpha[r];
    __syncthreads();
#pragma unroll
    for (int d2 = 0; d2 < 8; ++d2) {
#pragma unroll
      for (int kk = 0; kk < 2; ++kk) {
        short8 pa  = *(const short8*)&p_lds[w][l15][kk * 32 + q4 * 8];
        short8 vbf = *(const short8*)&vt_lds[d2 * 16 + l15][kk * 32 + q4 * 8];
        o_acc[d2] = mfma16(pa, vbf, o_acc[d2]);
      }
    }
  }
#pragma unroll
  for (int d2 = 0; d2 < 8; ++d2)
#pragma unroll
    for (int r = 0; r < 4; ++r) {
      int row = qt * 64 + w * 16 + q4 * 4 + r;
      float val = o_acc[d2][r] / l_i[r];
      ob[(size_t)(b * S_ + row) * (NH_ * DH_) + h * DH_ + d2 * 16 + l15] = f2b(val);
    }
}

extern "C" void kernel_launch(void* const* d_in, const int* in_sizes, int n_in,
                              void* d_out, int out_size, void* d_ws, size_t ws_size,
                              hipStream_t stream) {
  const float* hs   = (const float*)d_in[0];
  const float* cosb = (const float*)d_in[1];
  const float* sinb = (const float*)d_in[2];
  const float* wq   = (const float*)d_in[3];
  const float* wk   = (const float*)d_in[4];
  const float* wv   = (const float*)d_in[5];
  const float* wo   = (const float*)d_in[6];
  const float* qnw  = (const float*)d_in[7];
  const float* knw  = (const float*)d_in[8];
  const float* anw  = (const float*)d_in[9];
  const float* mnw  = (const float*)d_in[10];
  const float* wg   = (const float*)d_in[11];
  const float* wu   = (const float*)d_in[12];
  const float* wd   = (const float*)d_in[13];
  float* out = (float*)d_out;
  u16* ws  = (u16*)d_ws;

  // ws layout (u16 units), ~264 MB total
  u16* wqkvT = ws;                         //  6291456 (3072x2048: q rows 0-2047, k 2048-2559, v 2560-3071)
  u16* woT   = ws + 6291456;               //  4194304
  u16* wgT   = ws + 10485760;              // 16777216
  u16* wuT   = ws + 27262976;              // 16777216
  u16* wdT   = ws + 44040192;              // 16777216
  u16* xn    = ws + 60817408;              //  8388608 bf16 (rmsnorm1 out, later attn out)
  u16* qkv   = ws + 69206016;              // 12582912 bf16 (later reused as x2 = rmsnorm2 out)
  float* h1  = (float*)(ws + 81788928);    //  8388608 f32 (16777216 u16)
  u16* hbuf  = ws + 98566144;              // 33554432 bf16

  // weight convert+transpose (f32 KxN -> bf16 NxK)
  transpose_kernel<<<dim3(2048/64, 2048/64), 256, 0, stream>>>(wq, wqkvT, 2048, 2048);
  transpose_kernel<<<dim3(512/64,  2048/64), 256, 0, stream>>>(wk, wqkvT + (size_t)2048*2048, 2048, 512);
  transpose_kernel<<<dim3(512/64,  2048/64), 256, 0, stream>>>(wv, wqkvT + (size_t)2560*2048, 2048, 512);
  transpose_kernel<<<dim3(2048/64, 2048/64), 256, 0, stream>>>(wo, woT, 2048, 2048);
  transpose_kernel<<<dim3(8192/64, 2048/64), 256, 0, stream>>>(wg, wgT, 2048, 8192);
  transpose_kernel<<<dim3(8192/64, 2048/64), 256, 0, stream>>>(wu, wuT, 2048, 8192);
  transpose_kernel<<<dim3(2048/64, 8192/64), 256, 0, stream>>>(wd, wdT, 8192, 2048);

  rmsnorm_kernel<<<M_, 256, 0, stream>>>(hs, anw, xn);
  // fused QKV: (4096x2048) @ (2048x3072) -> qkv interleaved rows of 3072
  gemm_t<0><<<dim3(3072/128, M_/128), 256, 0, stream>>>(xn, wqkvT, qkv, nullptr, M_, 3072, 2048);
  qknorm_rope_kernel<<<M_ * NH_  / 4, 256, 0, stream>>>(qkv,        qnw, cosb, sinb, NH_,  3072);
  qknorm_rope_kernel<<<M_ * NKV_ / 4, 256, 0, stream>>>(qkv + 2048, knw, cosb, sinb, NKV_, 3072);
  attn_kernel<<<B_ * NH_ * (S_ / 64), 256, 0, stream>>>(qkv, qkv + 2048, qkv + 2560, xn);
  gemm_t<1><<<dim3(2048/128, M_/128), 256, 0, stream>>>(xn, woT, h1, hs, M_, 2048, 2048);
  u16* x2 = qkv;  // qkv dead after wo GEMM
  rmsnorm_kernel<<<M_, 256, 0, stream>>>(h1, mnw, x2);
  gateup_kernel<<<dim3(8192/128, M_/128), 256, 0, stream>>>(x2, wgT, wuT, hbuf, M_, 8192, 2048);
  gemm_t<1><<<dim3(2048/128, M_/128), 256, 0, stream>>>(hbuf, wdT, out, h1, M_, 2048, 8192);
}

// Round 4
// 1275.754 us; speedup vs baseline: 2.1538x; 1.2258x over previous
//
#include <hip/hip_runtime.h>
#include <stdint.h>

#define B_ 2
#define S_ 2048
#define H_ 2048
#define NH_ 16
#define NKV_ 4
#define DH_ 128
#define M_ (B_*S_)   // 4096 rows

typedef unsigned short u16;
typedef __attribute__((ext_vector_type(8))) short short8;
typedef __attribute__((ext_vector_type(4))) float floatx4;

__device__ __forceinline__ float b2f(u16 h) {
  union { unsigned int u; float f; } v; v.u = ((unsigned int)h) << 16; return v.f;
}
__device__ __forceinline__ u16 f2b(float f) {
  union { float f; unsigned int u; } v; v.f = f;
  unsigned int u = v.u;
  unsigned int r = (u + 0x7FFFu + ((u >> 16) & 1u)) >> 16;
  return (u16)r;
}
__device__ __forceinline__ floatx4 mfma16(short8 a, short8 b, floatx4 c) {
  return __builtin_amdgcn_mfma_f32_16x16x32_bf16(a, b, c, 0, 0, 0);
}
// async global->LDS, 16B per lane. LDS dest = wave-uniform base + lane*16.
__device__ __forceinline__ void gld16(const u16* g, u16* l) {
  __builtin_amdgcn_global_load_lds(
      (const __attribute__((address_space(1))) unsigned int*)g,
      (__attribute__((address_space(3))) unsigned int*)l, 16, 0, 0);
}

// ---- weight convert+transpose: f32 (K,N) -> bf16 (N,K), 64x64 tiles ------
__global__ __launch_bounds__(256) void transpose_kernel(const float* __restrict__ Bm,
                                                        u16* __restrict__ BT,
                                                        int K, int N) {
  __shared__ u16 sl[64][68];
  int t = threadIdx.x;
  int n0 = blockIdx.x * 64, k0 = blockIdx.y * 64;
#pragma unroll
  for (int p = 0; p < 4; ++p) {
    int kk = p * 16 + (t >> 4);
    int nn = (t & 15) * 4;
    float4 v = *(const float4*)&Bm[(size_t)(k0 + kk) * N + n0 + nn];
    sl[kk][nn + 0] = f2b(v.x); sl[kk][nn + 1] = f2b(v.y);
    sl[kk][nn + 2] = f2b(v.z); sl[kk][nn + 3] = f2b(v.w);
  }
  __syncthreads();
#pragma unroll
  for (int p = 0; p < 2; ++p) {
    int nn = p * 32 + (t >> 3);
    int kc = (t & 7) * 8;
    u16 ov[8];
#pragma unroll
    for (int j = 0; j < 8; ++j) ov[j] = sl[kc + j][nn];
    *(uint4*)&BT[(size_t)(n0 + nn) * K + k0 + kc] = *(uint4*)ov;
  }
}

// ---------------- RMSNorm over H=2048: f32 in, bf16 out. One row/block ----
__global__ __launch_bounds__(256) void rmsnorm_kernel(const float* __restrict__ x,
                                                      const float* __restrict__ w,
                                                      u16* __restrict__ o) {
  int row = blockIdx.x;
  int tid = threadIdx.x;
  const float* xr = x + (size_t)row * H_ + tid * 8;
  float4 a = *(const float4*)xr;
  float4 b = *(const float4*)(xr + 4);
  float xf[8] = {a.x, a.y, a.z, a.w, b.x, b.y, b.z, b.w};
  float ss = 0.f;
#pragma unroll
  for (int i = 0; i < 8; ++i) ss += xf[i] * xf[i];
#pragma unroll
  for (int m = 32; m >= 1; m >>= 1) ss += __shfl_xor(ss, m, 64);
  __shared__ float red[4];
  if ((tid & 63) == 0) red[tid >> 6] = ss;
  __syncthreads();
  float tot = red[0] + red[1] + red[2] + red[3];
  float scale = rsqrtf(tot / (float)H_ + 1e-6f);
  const float* wr = w + tid * 8;
  float4 wa = *(const float4*)wr;
  float4 wb = *(const float4*)(wr + 4);
  float wf[8] = {wa.x, wa.y, wa.z, wa.w, wb.x, wb.y, wb.z, wb.w};
  u16 ov[8];
#pragma unroll
  for (int i = 0; i < 8; ++i) ov[i] = f2b(xf[i] * scale * wf[i]);
  *(uint4*)&o[(size_t)row * H_ + tid * 8] = *(uint4*)ov;
}

// ---- m97-style GEMM: C(M,N) = A_bf16(M,K) @ BT_bf16(N,K)^T [+Res_f32] ----
template <int OUTF>   // 0: bf16 out; 1: f32 out (+Res if non-null)
__global__ __launch_bounds__(256) void gemm_t(const u16* __restrict__ A,
                                              const u16* __restrict__ BT,
                                              void* __restrict__ Cv,
                                              const float* __restrict__ Res,
                                              int M, int N, int K) {
  __shared__ u16 sa[128 * 32];
  __shared__ u16 sb[128 * 32];
  const int tid = threadIdx.x;
  const int lane = tid & 63, w = tid >> 6;
  const int q4 = lane >> 4, l15 = lane & 15;
  const int wr = (w >> 1) * 64, wc = (w & 1) * 64;
  const int m0 = blockIdx.y * 128, n0 = blockIdx.x * 128;
  const int srow = lane >> 2, skc = (lane & 3) * 8;
  const int c0 = w * 2;
  floatx4 acc[4][4] = {};
  const u16* aG0 = A  + (size_t)(m0 + (c0 + 0) * 16 + srow) * K + skc;
  const u16* aG1 = A  + (size_t)(m0 + (c0 + 1) * 16 + srow) * K + skc;
  const u16* bG0 = BT + (size_t)(n0 + (c0 + 0) * 16 + srow) * K + skc;
  const u16* bG1 = BT + (size_t)(n0 + (c0 + 1) * 16 + srow) * K + skc;
  u16* aL0 = sa + (c0 + 0) * 512;
  u16* aL1 = sa + (c0 + 1) * 512;
  u16* bL0 = sb + (c0 + 0) * 512;
  u16* bL1 = sb + (c0 + 1) * 512;

  for (int k0 = 0; k0 < K; k0 += 32) {
    __syncthreads();
    gld16(aG0 + k0, aL0);
    gld16(aG1 + k0, aL1);
    gld16(bG0 + k0, bL0);
    gld16(bG1 + k0, bL1);
    __syncthreads();
    short8 af[4], bf[4];
#pragma unroll
    for (int i = 0; i < 4; ++i)
      af[i] = *(const short8*)&sa[(wr + i * 16 + l15) * 32 + q4 * 8];
#pragma unroll
    for (int j = 0; j < 4; ++j)
      bf[j] = *(const short8*)&sb[(wc + j * 16 + l15) * 32 + q4 * 8];
#pragma unroll
    for (int i = 0; i < 4; ++i)
#pragma unroll
      for (int j = 0; j < 4; ++j)
        acc[i][j] = mfma16(af[i], bf[j], acc[i][j]);
  }
#pragma unroll
  for (int i = 0; i < 4; ++i)
#pragma unroll
    for (int j = 0; j < 4; ++j)
#pragma unroll
      for (int r = 0; r < 4; ++r) {
        int row = m0 + wr + i * 16 + q4 * 4 + r;
        int col = n0 + wc + j * 16 + l15;
        float v = acc[i][j][r];
        if (OUTF) {
          if (Res) v += Res[(size_t)row * N + col];
          ((float*)Cv)[(size_t)row * N + col] = v;
        } else {
          ((u16*)Cv)[(size_t)row * N + col] = f2b(v);
        }
      }
}

// ---- fused gate/up GEMM + SiLU: 128x64 block, dual accumulators ----------
// Each block computes a 64-wide N strip of BOTH g and u (64 AGPR/wave total),
// per-wave 16 MFMA : 4 gld16 per K-step == m97 profile; 16 KB LDS.
__global__ __launch_bounds__(256) void gateup_kernel(const u16* __restrict__ A,
                                                     const u16* __restrict__ GT,
                                                     const u16* __restrict__ UT,
                                                     u16* __restrict__ O,
                                                     int M, int N, int K) {
  __shared__ u16 sa[128 * 32];
  __shared__ u16 sg[64 * 32];
  __shared__ u16 su[64 * 32];
  const int tid = threadIdx.x;
  const int lane = tid & 63, w = tid >> 6;
  const int q4 = lane >> 4, l15 = lane & 15;
  const int wr = (w >> 1) * 64, wc = (w & 1) * 32;
  const int m0 = blockIdx.y * 128, n0 = blockIdx.x * 64;
  const int srow = lane >> 2, skc = (lane & 3) * 8;
  const int c0 = w * 2;
  floatx4 accg[4][2] = {};
  floatx4 accu[4][2] = {};
  const u16* aG0 = A  + (size_t)(m0 + (c0 + 0) * 16 + srow) * K + skc;
  const u16* aG1 = A  + (size_t)(m0 + (c0 + 1) * 16 + srow) * K + skc;
  const u16* gG  = GT + (size_t)(n0 + w * 16 + srow) * K + skc;
  const u16* uG  = UT + (size_t)(n0 + w * 16 + srow) * K + skc;
  u16* aL0 = sa + (c0 + 0) * 512;
  u16* aL1 = sa + (c0 + 1) * 512;
  u16* gL  = sg + w * 512;
  u16* uL  = su + w * 512;

  for (int k0 = 0; k0 < K; k0 += 32) {
    __syncthreads();
    gld16(aG0 + k0, aL0);
    gld16(aG1 + k0, aL1);
    gld16(gG + k0, gL);
    gld16(uG + k0, uL);
    __syncthreads();
    short8 af[4], gf[2], uf[2];
#pragma unroll
    for (int i = 0; i < 4; ++i)
      af[i] = *(const short8*)&sa[(wr + i * 16 + l15) * 32 + q4 * 8];
#pragma unroll
    for (int j = 0; j < 2; ++j) {
      gf[j] = *(const short8*)&sg[(wc + j * 16 + l15) * 32 + q4 * 8];
      uf[j] = *(const short8*)&su[(wc + j * 16 + l15) * 32 + q4 * 8];
    }
#pragma unroll
    for (int i = 0; i < 4; ++i)
#pragma unroll
      for (int j = 0; j < 2; ++j) {
        accg[i][j] = mfma16(af[i], gf[j], accg[i][j]);
        accu[i][j] = mfma16(af[i], uf[j], accu[i][j]);
      }
  }
#pragma unroll
  for (int i = 0; i < 4; ++i)
#pragma unroll
    for (int j = 0; j < 2; ++j)
#pragma unroll
      for (int r = 0; r < 4; ++r) {
        int row = m0 + wr + i * 16 + q4 * 4 + r;
        int col = n0 + wc + j * 16 + l15;
        float g = accg[i][j][r];
        float u = accu[i][j][r];
        float s = g / (1.f + __expf(-g));
        O[(size_t)row * N + col] = f2b(s * u);
      }
}

// ------- per-head RMSNorm + RoPE (in place on bf16), 1 wave per (t,h) -----
__global__ __launch_bounds__(256) void qknorm_rope_kernel(u16* __restrict__ x,
                                                          const float* __restrict__ nw,
                                                          const float* __restrict__ cs,
                                                          const float* __restrict__ sn,
                                                          int nheads, int rowStride) {
  int lane = threadIdx.x & 63;
  int w = threadIdx.x >> 6;
  int gw = blockIdx.x * 4 + w;
  int t = gw / nheads, h = gw % nheads;
  u16* xp = x + (size_t)t * rowStride + h * DH_;
  float x0 = b2f(xp[lane]), x1 = b2f(xp[lane + 64]);
  float ss = x0 * x0 + x1 * x1;
#pragma unroll
  for (int m = 32; m >= 1; m >>= 1) ss += __shfl_xor(ss, m, 64);
  float scale = rsqrtf(ss / 128.f + 1e-6f);
  float n0 = x0 * scale * nw[lane];
  float n1 = x1 * scale * nw[lane + 64];
  const float* cp = cs + (size_t)t * DH_;
  const float* sp = sn + (size_t)t * DH_;
  float c0 = cp[lane], c1 = cp[lane + 64];
  float s0 = sp[lane], s1 = sp[lane + 64];
  xp[lane]      = f2b(n0 * c0 - n1 * s0);
  xp[lane + 64] = f2b(n1 * c1 + n0 * s1);
}

// ---------------- flash attention (full, non-causal), GQA, all bf16 -------
__global__ __launch_bounds__(256) void attn_kernel(const u16* __restrict__ qb,
                                                   const u16* __restrict__ kb,
                                                   const u16* __restrict__ vb,
                                                   u16* __restrict__ ob) {
  __shared__ u16 q_lds[64][136];
  __shared__ u16 k_lds[64][136];
  __shared__ u16 vt_lds[128][72];   // [d][j]
  __shared__ u16 p_lds[4][16][72];  // per wave [qrow][j]
  const int QSTR = NH_ * DH_ + NKV_ * DH_ * 2;  // 3072 row stride in qkv buffer
  int tid = threadIdx.x;
  int lane = tid & 63, w = tid >> 6;
  int q4 = lane >> 4, l15 = lane & 15;
  int qt = blockIdx.x & 31;
  int h = (blockIdx.x >> 5) & 15;
  int b = blockIdx.x >> 9;
  int kvh = h >> 2;
  int srow = tid >> 2;
  int sd0 = (tid & 3) * 32;
  const float scaling = 0.08838834764831845f;

  {
    const u16* qsrc = qb + (size_t)(b * S_ + qt * 64 + srow) * QSTR + h * DH_;
#pragma unroll
    for (int ii = 0; ii < 4; ++ii) {
      int d = sd0 + ii * 8;
      *(uint4*)&q_lds[srow][d] = *(const uint4*)&qsrc[d];
    }
  }

  float m_i[4], l_i[4];
  floatx4 o_acc[8] = {};
#pragma unroll
  for (int r = 0; r < 4; ++r) { m_i[r] = -1e30f; l_i[r] = 0.f; }

  for (int c = 0; c < S_ / 64; ++c) {
    int j0 = c * 64;
    __syncthreads();
    const u16* ksrc = kb + (size_t)(b * S_ + j0 + srow) * QSTR + kvh * DH_;
    const u16* vsrc = vb + (size_t)(b * S_ + j0 + srow) * QSTR + kvh * DH_;
#pragma unroll
    for (int ii = 0; ii < 4; ++ii) {
      int d = sd0 + ii * 8;
      *(uint4*)&k_lds[srow][d] = *(const uint4*)&ksrc[d];
      uint4 vv = *(const uint4*)&vsrc[d];
      const u16* ve = (const u16*)&vv;
#pragma unroll
      for (int e = 0; e < 8; ++e) vt_lds[d + e][srow] = ve[e];
    }
    __syncthreads();

    floatx4 sc[4];
#pragma unroll
    for (int js = 0; js < 4; ++js) {
      floatx4 a = {};
#pragma unroll
      for (int kk = 0; kk < 4; ++kk) {
        short8 qa  = *(const short8*)&q_lds[w * 16 + l15][kk * 32 + q4 * 8];
        short8 kbf = *(const short8*)&k_lds[js * 16 + l15][kk * 32 + q4 * 8];
        a = mfma16(qa, kbf, a);
      }
      sc[js] = a;
    }
    float mx[4];
#pragma unroll
    for (int r = 0; r < 4; ++r)
      mx[r] = fmaxf(fmaxf(sc[0][r], sc[1][r]), fmaxf(sc[2][r], sc[3][r])) * scaling;
#pragma unroll
    for (int m = 8; m >= 1; m >>= 1)
#pragma unroll
      for (int r = 0; r < 4; ++r) mx[r] = fmaxf(mx[r], __shfl_xor(mx[r], m, 64));
    float alpha[4], rs[4];
#pragma unroll
    for (int r = 0; r < 4; ++r) {
      float mnew = fmaxf(m_i[r], mx[r]);
      alpha[r] = __expf(m_i[r] - mnew);
      m_i[r] = mnew;
      rs[r] = 0.f;
    }
#pragma unroll
    for (int js = 0; js < 4; ++js)
#pragma unroll
      for (int r = 0; r < 4; ++r) {
        float p = __expf(sc[js][r] * scaling - m_i[r]);
        rs[r] += p;
        p_lds[w][q4 * 4 + r][js * 16 + l15] = f2b(p);
      }
#pragma unroll
    for (int m = 8; m >= 1; m >>= 1)
#pragma unroll
      for (int r = 0; r < 4; ++r) rs[r] += __shfl_xor(rs[r], m, 64);
#pragma unroll
    for (int r = 0; r < 4; ++r) l_i[r] = l_i[r] * alpha[r] + rs[r];
#pragma unroll
    for (int d2 = 0; d2 < 8; ++d2)
#pragma unroll
      for (int r = 0; r < 4; ++r) o_acc[d2][r] *= alpha[r];
    __syncthreads();
#pragma unroll
    for (int d2 = 0; d2 < 8; ++d2) {
#pragma unroll
      for (int kk = 0; kk < 2; ++kk) {
        short8 pa  = *(const short8*)&p_lds[w][l15][kk * 32 + q4 * 8];
        short8 vbf = *(const short8*)&vt_lds[d2 * 16 + l15][kk * 32 + q4 * 8];
        o_acc[d2] = mfma16(pa, vbf, o_acc[d2]);
      }
    }
  }
#pragma unroll
  for (int d2 = 0; d2 < 8; ++d2)
#pragma unroll
    for (int r = 0; r < 4; ++r) {
      int row = qt * 64 + w * 16 + q4 * 4 + r;
      float val = o_acc[d2][r] / l_i[r];
      ob[(size_t)(b * S_ + row) * (NH_ * DH_) + h * DH_ + d2 * 16 + l15] = f2b(val);
    }
}

extern "C" void kernel_launch(void* const* d_in, const int* in_sizes, int n_in,
                              void* d_out, int out_size, void* d_ws, size_t ws_size,
                              hipStream_t stream) {
  const float* hs   = (const float*)d_in[0];
  const float* cosb = (const float*)d_in[1];
  const float* sinb = (const float*)d_in[2];
  const float* wq   = (const float*)d_in[3];
  const float* wk   = (const float*)d_in[4];
  const float* wv   = (const float*)d_in[5];
  const float* wo   = (const float*)d_in[6];
  const float* qnw  = (const float*)d_in[7];
  const float* knw  = (const float*)d_in[8];
  const float* anw  = (const float*)d_in[9];
  const float* mnw  = (const float*)d_in[10];
  const float* wg   = (const float*)d_in[11];
  const float* wu   = (const float*)d_in[12];
  const float* wd   = (const float*)d_in[13];
  float* out = (float*)d_out;
  u16* ws  = (u16*)d_ws;

  // ws layout (u16 units), ~264 MB total
  u16* wqkvT = ws;                         //  6291456 (3072x2048: q rows 0-2047, k 2048-2559, v 2560-3071)
  u16* woT   = ws + 6291456;               //  4194304
  u16* wgT   = ws + 10485760;              // 16777216
  u16* wuT   = ws + 27262976;              // 16777216
  u16* wdT   = ws + 44040192;              // 16777216
  u16* xn    = ws + 60817408;              //  8388608 bf16 (rmsnorm1 out, later attn out)
  u16* qkv   = ws + 69206016;              // 12582912 bf16 (later reused as x2 = rmsnorm2 out)
  float* h1  = (float*)(ws + 81788928);    //  8388608 f32 (16777216 u16)
  u16* hbuf  = ws + 98566144;              // 33554432 bf16

  // weight convert+transpose (f32 KxN -> bf16 NxK)
  transpose_kernel<<<dim3(2048/64, 2048/64), 256, 0, stream>>>(wq, wqkvT, 2048, 2048);
  transpose_kernel<<<dim3(512/64,  2048/64), 256, 0, stream>>>(wk, wqkvT + (size_t)2048*2048, 2048, 512);
  transpose_kernel<<<dim3(512/64,  2048/64), 256, 0, stream>>>(wv, wqkvT + (size_t)2560*2048, 2048, 512);
  transpose_kernel<<<dim3(2048/64, 2048/64), 256, 0, stream>>>(wo, woT, 2048, 2048);
  transpose_kernel<<<dim3(8192/64, 2048/64), 256, 0, stream>>>(wg, wgT, 2048, 8192);
  transpose_kernel<<<dim3(8192/64, 2048/64), 256, 0, stream>>>(wu, wuT, 2048, 8192);
  transpose_kernel<<<dim3(2048/64, 8192/64), 256, 0, stream>>>(wd, wdT, 8192, 2048);

  rmsnorm_kernel<<<M_, 256, 0, stream>>>(hs, anw, xn);
  gemm_t<0><<<dim3(3072/128, M_/128), 256, 0, stream>>>(xn, wqkvT, qkv, nullptr, M_, 3072, 2048);
  qknorm_rope_kernel<<<M_ * NH_  / 4, 256, 0, stream>>>(qkv,        qnw, cosb, sinb, NH_,  3072);
  qknorm_rope_kernel<<<M_ * NKV_ / 4, 256, 0, stream>>>(qkv + 2048, knw, cosb, sinb, NKV_, 3072);
  attn_kernel<<<B_ * NH_ * (S_ / 64), 256, 0, stream>>>(qkv, qkv + 2048, qkv + 2560, xn);
  gemm_t<1><<<dim3(2048/128, M_/128), 256, 0, stream>>>(xn, woT, h1, hs, M_, 2048, 2048);
  u16* x2 = qkv;  // qkv dead after wo GEMM
  rmsnorm_kernel<<<M_, 256, 0, stream>>>(h1, mnw, x2);
  gateup_kernel<<<dim3(8192/64, M_/128), 256, 0, stream>>>(x2, wgT, wuT, hbuf, M_, 8192, 2048);
  gemm_t<1><<<dim3(2048/128, M_/128), 256, 0, stream>>>(hbuf, wdT, out, h1, M_, 2048, 8192);
}